// Round 2
// baseline (2395.477 us; speedup 1.0000x reference)
//
#include <hip/hip_runtime.h>
#include <hip/hip_cooperative_groups.h>

namespace cg = cooperative_groups;

#define L 32
#define W 262144
#define NN (L * W)
#define NTH (W / 2)        // 2 nodes per thread -> 131072 threads
#define NBLK (NTH / 256)   // 512 blocks, 256 threads each (2 blocks/CU)

// Persistent cooperative kernel: whole DAG evaluation in one launch.
// Level-l children live in [0, l*W). Before this level's grid.sync(), the
// span [0,(l-1)*W) is already final+visible (previous sync), so those
// gathers issue speculatively and complete in the barrier's shadow; only
// children in the newest level gather post-barrier.
__global__ __launch_bounds__(256, 2) void recnn_coop(
    const float* __restrict__ values,
    const int4* __restrict__ idx4,    // child_idx as [(L-1)*W/2] int4 (2 nodes/thread)
    const int2* __restrict__ typ2,    // node_types as [(L-1)*W/2] int2
    const float* __restrict__ w_term,
    const float* __restrict__ w_plus,
    const float* __restrict__ w_minus,
    const float* __restrict__ w_final,
    const float* __restrict__ b_final,
    float* __restrict__ outs,         // [NN] workspace
    float* __restrict__ out)          // [1]
{
    cg::grid_group grid = cg::this_grid();
    const int i = blockIdx.x * 256 + threadIdx.x;   // [0, W/2)

    const float wt  = w_term[0];
    const float wp0 = w_plus[0],  wp1 = w_plus[1];
    const float wm0 = w_minus[0], wm1 = w_minus[1];

    // ---- level 0: terminal nodes ----
    const float2 v = ((const float2*)values)[i];
    float2 o0;
    o0.x = v.x * wt;
    o0.y = v.y * wt;
    ((float2*)outs)[i] = o0;

    // preload level-1 structure (independent of outputs)
    int4 c = idx4[i];
    int2 t = typ2[i];

    for (int l = 1; l < L; ++l) {
        const int safe = (l - 1) * W;   // final+visible span before this sync
        float xa0 = 0.f, xa1 = 0.f, xb0 = 0.f, xb1 = 0.f;
        const bool pa0 = c.x < safe, pa1 = c.y < safe;
        const bool pb0 = c.z < safe, pb1 = c.w < safe;
        if (pa0) xa0 = outs[c.x];
        if (pa1) xa1 = outs[c.y];
        if (pb0) xb0 = outs[c.z];
        if (pb1) xb1 = outs[c.w];

        grid.sync();   // makes level l-1 outputs visible device-wide

        if (!pa0) xa0 = outs[c.x];
        if (!pa1) xa1 = outs[c.y];
        if (!pb0) xb0 = outs[c.z];
        if (!pb1) xb1 = outs[c.w];

        float2 o;
        o.x = (t.x == 1) ? fmaf(xa0, wp0, xa1 * wp1) : fmaf(xa0, wm0, xa1 * wm1);
        o.y = (t.y == 1) ? fmaf(xb0, wp0, xb1 * wp1) : fmaf(xb0, wm0, xb1 * wm1);
        ((float2*)(outs + (size_t)l * W))[i] = o;

        if (l + 1 < L) {   // preload next level's structure before its barrier
            c = idx4[(size_t)l * NTH + i];
            t = typ2[(size_t)l * NTH + i];
        }
    }

    grid.sync();   // make last level visible
    if (i == 0) out[0] = fmaf(outs[NN - 1], w_final[0], b_final[0]);
}

extern "C" void kernel_launch(void* const* d_in, const int* in_sizes, int n_in,
                              void* d_out, int out_size, void* d_ws, size_t ws_size,
                              hipStream_t stream) {
    const float* values     = (const float*)d_in[0];
    const int*   child_idx  = (const int*)d_in[1];   // [L-1, W, 2]
    const int*   node_types = (const int*)d_in[2];   // [L-1, W]
    const float* w_term     = (const float*)d_in[3];
    const float* w_plus     = (const float*)d_in[4];
    const float* w_minus    = (const float*)d_in[5];
    const float* w_final    = (const float*)d_in[6];
    const float* b_final    = (const float*)d_in[7];

    float* outs = (float*)d_ws;     // NN floats = 33.5 MB
    float* out  = (float*)d_out;

    void* args[] = {
        (void*)&values, (void*)&child_idx, (void*)&node_types,
        (void*)&w_term, (void*)&w_plus, (void*)&w_minus,
        (void*)&w_final, (void*)&b_final, (void*)&outs, (void*)&out
    };
    hipLaunchCooperativeKernel((void*)recnn_coop,
                               dim3(NBLK), dim3(256),
                               args, 0, stream);
}

// Round 3
// 135.196 us; speedup vs baseline: 17.7185x; 17.7185x over previous
//
#include <hip/hip_runtime.h>

#define L 32
#define W 262144              // 2^18
#define NN (L * W)
#define CAP 2048              // cone capacity; expected cone size = 2*31+1 = 63
#define MAXR 36

// The final output depends only on the dependency cone of node NN-1.
// Children of a level-l node have index < l*W (strictly lower level), so the
// cone has expected size 2L-1 = 63 and depth <= 31. BFS-expand the cone
// (each round = one parallel batch of random gathers), then evaluate
// bottom-up entirely in LDS.
//
// Node n >= W: level l = n>>18, within-level w = n & (W-1);
//   flat row = (l-1)*W + w = n - W  (for both child_idx and node_types).
__global__ __launch_bounds__(256) void recnn_cone(
    const float* __restrict__ values,
    const int2*  __restrict__ cidx,    // child_idx as [(L-1)*W] int2
    const int*   __restrict__ ntype,   // node_types  [(L-1)*W]
    const float* __restrict__ w_term,
    const float* __restrict__ w_plus,
    const float* __restrict__ w_minus,
    const float* __restrict__ w_final,
    const float* __restrict__ b_final,
    float* __restrict__ out)
{
    __shared__ int   s_node[CAP];
    __shared__ int   s_type[CAP];   // 0 = leaf/terminal (val ready), 1 = plus, 2 = minus
    __shared__ int   s_c0[CAP];     // child slots are s_c0[i], s_c0[i]+1
    __shared__ float s_val[CAP];
    __shared__ int   s_cnt;
    __shared__ int   rb[MAXR];      // round boundaries: round r = [rb[r], rb[r+1])

    const int tid = threadIdx.x;
    const float wt  = w_term[0];
    const float wp0 = w_plus[0],  wp1 = w_plus[1];
    const float wm0 = w_minus[0], wm1 = w_minus[1];

    if (tid == 0) { s_node[0] = NN - 1; s_cnt = 1; rb[0] = 0; rb[1] = 1; }
    __syncthreads();

    // ---- top-down BFS expansion ----
    int fs = 0, fe = 1, nr = 0;
    while (fs < fe && nr < 32) {
        for (int i = fs + tid; i < fe; i += 256) {
            int n = s_node[i];
            if (n >= W) {
                int2 c  = cidx[n - W];       // random gather (8B)
                int  ty = ntype[n - W];      // random gather (4B), same line region
                int slot = atomicAdd(&s_cnt, 2);
                if (slot + 1 < CAP) {
                    s_node[slot]     = c.x;
                    s_node[slot + 1] = c.y;
                    s_c0[i]   = slot;
                    s_type[i] = ty;
                } else {                     // overflow guard (never expected)
                    s_type[i] = 0;
                    s_val[i]  = 0.0f;
                }
            } else {                         // terminal node
                s_type[i] = 0;
                s_val[i]  = values[n] * wt;  // random gather (4B)
            }
        }
        __syncthreads();
        fs = fe;
        fe = min(s_cnt, CAP);
        nr++;
        if (tid == 0) rb[nr + 1] = fe;
        __syncthreads();
    }

    // ---- bottom-up evaluation (children of round r live in round r+1) ----
    for (int r = nr - 1; r >= 0; --r) {
        for (int i = rb[r] + tid; i < rb[r + 1]; i += 256) {
            int ty = s_type[i];
            if (ty != 0) {
                int   c0 = s_c0[i];
                float x0 = s_val[c0], x1 = s_val[c0 + 1];
                s_val[i] = (ty == 1) ? fmaf(x0, wp0, x1 * wp1)
                                     : fmaf(x0, wm0, x1 * wm1);
            }
        }
        __syncthreads();
    }

    if (tid == 0) out[0] = fmaf(s_val[0], w_final[0], b_final[0]);
}

extern "C" void kernel_launch(void* const* d_in, const int* in_sizes, int n_in,
                              void* d_out, int out_size, void* d_ws, size_t ws_size,
                              hipStream_t stream) {
    const float* values     = (const float*)d_in[0];
    const int*   child_idx  = (const int*)d_in[1];   // [L-1, W, 2]
    const int*   node_types = (const int*)d_in[2];   // [L-1, W]
    const float* w_term     = (const float*)d_in[3];
    const float* w_plus     = (const float*)d_in[4];
    const float* w_minus    = (const float*)d_in[5];
    const float* w_final    = (const float*)d_in[6];
    const float* b_final    = (const float*)d_in[7];

    float* out = (float*)d_out;

    recnn_cone<<<1, 256, 0, stream>>>(
        values, (const int2*)child_idx, node_types,
        w_term, w_plus, w_minus, w_final, b_final, out);
}

// Round 4
// 134.433 us; speedup vs baseline: 17.8191x; 1.0057x over previous
//
#include <hip/hip_runtime.h>

#define L 32
#define W 262144              // 2^18
#define NN (L * W)
#define CAP 2048              // cone capacity; expected cone size = 2*31+1 = 63
#define MAXR 40

// Only the dependency cone of node NN-1 matters (~63 nodes expected, depth
// <= 31, typically ~10). BFS-expand top-down (each round = one parallel
// batch of random gathers, latency-bound), then evaluate bottom-up in LDS.
// Single wave (64 lanes): barriers are nearly free, the latency chain
// (depth x cold-gather) is the floor.
//
// Node n >= W maps to flat row n - W in child_idx/node_types.
__global__ __launch_bounds__(64) void recnn_cone(
    const float* __restrict__ values,
    const int2*  __restrict__ cidx,    // child_idx as [(L-1)*W] int2
    const int*   __restrict__ ntype,   // node_types  [(L-1)*W]
    const float* __restrict__ w_term,
    const float* __restrict__ w_plus,
    const float* __restrict__ w_minus,
    const float* __restrict__ w_final,
    const float* __restrict__ b_final,
    float* __restrict__ out)
{
    __shared__ int   s_node[CAP];
    __shared__ int   s_type[CAP];   // 0 = leaf (val ready), 1 = plus, 2 = minus
    __shared__ int   s_c0[CAP];     // child slots: s_c0[i], s_c0[i]+1
    __shared__ float s_val[CAP];
    __shared__ int   s_cnt;
    __shared__ int   rb[MAXR];      // round r occupies [rb[r], rb[r+1])

    const int tid = threadIdx.x;
    const float wt  = w_term[0];
    const float wp0 = w_plus[0],  wp1 = w_plus[1];
    const float wm0 = w_minus[0], wm1 = w_minus[1];

    if (tid == 0) { s_node[0] = NN - 1; s_cnt = 1; rb[0] = 0; rb[1] = 1; }
    __syncthreads();

    // ---- top-down BFS expansion ----
    int fs = 0, fe = 1, nr = 0;
    while (fs < fe && nr < 32) {
        for (int i = fs + tid; i < fe; i += 64) {
            int n = s_node[i];
            if (n >= W) {
                int2 c  = cidx[n - W];       // random 8B gather
                int  ty = ntype[n - W];      // random 4B gather (concurrent)
                int slot = atomicAdd(&s_cnt, 2);
                if (slot + 1 < CAP) {
                    s_node[slot]     = c.x;
                    s_node[slot + 1] = c.y;
                    s_c0[i]   = slot;
                    s_type[i] = ty;
                } else {                     // overflow guard (never expected)
                    s_type[i] = 0;
                    s_val[i]  = 0.0f;
                }
            } else {                         // terminal node
                s_type[i] = 0;
                s_val[i]  = values[n] * wt;  // random 4B gather
            }
        }
        __syncthreads();
        fs = fe;
        fe = min(s_cnt, CAP);
        nr++;
        if (tid == 0) rb[nr + 1] = fe;
        __syncthreads();
    }

    // ---- bottom-up evaluation (children of round r live in rounds > r) ----
    for (int r = nr - 1; r >= 0; --r) {
        for (int i = rb[r] + tid; i < rb[r + 1]; i += 64) {
            int ty = s_type[i];
            if (ty != 0) {
                int   c0 = s_c0[i];
                float x0 = s_val[c0], x1 = s_val[c0 + 1];
                s_val[i] = (ty == 1) ? fmaf(x0, wp0, x1 * wp1)
                                     : fmaf(x0, wm0, x1 * wm1);
            }
        }
        __syncthreads();
    }

    if (tid == 0) out[0] = fmaf(s_val[0], w_final[0], b_final[0]);
}

extern "C" void kernel_launch(void* const* d_in, const int* in_sizes, int n_in,
                              void* d_out, int out_size, void* d_ws, size_t ws_size,
                              hipStream_t stream) {
    const float* values     = (const float*)d_in[0];
    const int*   child_idx  = (const int*)d_in[1];   // [L-1, W, 2]
    const int*   node_types = (const int*)d_in[2];   // [L-1, W]
    const float* w_term     = (const float*)d_in[3];
    const float* w_plus     = (const float*)d_in[4];
    const float* w_minus    = (const float*)d_in[5];
    const float* w_final    = (const float*)d_in[6];
    const float* b_final    = (const float*)d_in[7];

    float* out = (float*)d_out;

    recnn_cone<<<1, 64, 0, stream>>>(
        values, (const int2*)child_idx, node_types,
        w_term, w_plus, w_minus, w_final, b_final, out);
}